// Round 3
// baseline (157.378 us; speedup 1.0000x reference)
//
#include <hip/hip_runtime.h>
#include <hip/hip_bf16.h>

// Shift SSM == causal 64-tap FIR per channel + skip connection.
//   K[h,k] = sum_{s=0}^{63-k} B[h,s] * C[0,h,k+s]   (D folded into K[h,0])
//   y[b,h,l] = sum_{k=0}^{63} K[h,k] * u[b,h,l-k]
//
// R3 structure: NO LDS staging of u (R2 was LDS-pipe bound: 512 wave-b128
// reads/block ~ 7.8k LDS cycles vs 2.3k FMA cycles/SIMD). Instead each
// thread slides a 3x16-float register window fed directly from global;
// neighboring threads share 64B cache lines (5x L1 hits). LDS only holds
// the 64 taps (broadcast reads = conflict-free).

#define D_MODEL 512
#define D_STATE 64
#define BATCH   8
#define SEQ_L   4096
#define NT      256

__global__ void __launch_bounds__(NT, 4)
shift_fused(const float* __restrict__ u,
            const float* __restrict__ B,
            const float* __restrict__ C,
            const float* __restrict__ D,
            float* __restrict__ y) {
    const int row = blockIdx.x;              // b*512 + h
    const int h   = row & (D_MODEL - 1);
    const float* __restrict__ urow = u + (size_t)row * SEQ_L;
    float* __restrict__ yrow       = y + (size_t)row * SEQ_L;

    __shared__ float Bs[D_STATE];
    __shared__ float Cs[2 * D_STATE];        // C row + zero pad (kills bound check)
    __shared__ float K[D_STATE];

    const int t    = threadIdx.x;            // 0..255
    const int out0 = t << 4;                 // 16 outputs per thread

    // ---- window buffers: issue global loads early (in flight across barriers) ----
    float wa[16], wb[16], wc[16];
    auto load16 = [&](float* w, int base) {  // base is a multiple of 16
        if (base >= 0) {
            #pragma unroll
            for (int j = 0; j < 4; ++j) {
                const float4 v = *(const float4*)(urow + base + 4 * j);
                w[4*j + 0] = v.x; w[4*j + 1] = v.y;
                w[4*j + 2] = v.z; w[4*j + 3] = v.w;
            }
        } else {
            #pragma unroll
            for (int j = 0; j < 16; ++j) w[j] = 0.f;
        }
    };
    load16(wa, out0);                        // hi of chunk 0 (always valid)
    load16(wb, out0 - 16);                   // lo of chunk 0
    load16(wc, out0 - 32);                   // lo of chunk 1 (prefetch)

    // ---- taps: stage B,C rows -> LDS, then 64 lanes compute K ----
    if (t < 16) {
        ((float4*)Bs)[t] = ((const float4*)(B + h * D_STATE))[t];
    } else if (t < 48) {
        const int j = t - 16;                // 0..31
        ((float4*)Cs)[j] = (j < 16) ? ((const float4*)(C + h * D_STATE))[j]
                                    : make_float4(0.f, 0.f, 0.f, 0.f);
    }
    __syncthreads();
    if (t < D_STATE) {
        float s = 0.f;
        #pragma unroll
        for (int j = 0; j < D_STATE; ++j)
            s = fmaf(Bs[j], Cs[t + j], s);   // Cs zero-padded: no bound check
        if (t == 0) s += D[h];
        K[t] = s;
    }
    __syncthreads();

    // ---- FIR: 4 tap-chunks of 16, sliding register window ----
    float acc[16];
    #pragma unroll
    for (int i = 0; i < 16; ++i) acc[i] = 0.f;

    const float4* K4 = (const float4*)K;
    auto chunk = [&](int kk, const float* hi, const float* lo) {
        #pragma unroll
        for (int qj = 0; qj < 4; ++qj) {
            const float4 kv = K4[4 * kk + qj];   // LDS broadcast b128
            const float kq[4] = {kv.x, kv.y, kv.z, kv.w};
            #pragma unroll
            for (int qq = 0; qq < 4; ++qq) {
                const int q = 4 * qj + qq;       // tap within chunk
                #pragma unroll
                for (int i = 0; i < 16; ++i) {
                    const int widx = 16 + i - q; // 1..31, compile-time
                    const float wv = (widx >= 16) ? hi[widx - 16] : lo[widx];
                    acc[i] = fmaf(kq[qq], wv, acc[i]);
                }
            }
        }
    };

    chunk(0, wa, wb);
    load16(wa, out0 - 48);                   // lo of chunk 2
    chunk(1, wb, wc);
    load16(wb, out0 - 64);                   // lo of chunk 3
    chunk(2, wc, wa);
    chunk(3, wa, wb);

    #pragma unroll
    for (int j = 0; j < 4; ++j) {
        float4 o;
        o.x = acc[4*j + 0]; o.y = acc[4*j + 1];
        o.z = acc[4*j + 2]; o.w = acc[4*j + 3];
        *(float4*)(yrow + out0 + 4*j) = o;
    }
}

extern "C" void kernel_launch(void* const* d_in, const int* in_sizes, int n_in,
                              void* d_out, int out_size, void* d_ws, size_t ws_size,
                              hipStream_t stream) {
    const float* u = (const float*)d_in[0];   // (8, 512, 4096)
    const float* B = (const float*)d_in[1];   // (512, 64)
    const float* C = (const float*)d_in[2];   // (1, 512, 64)
    const float* D = (const float*)d_in[3];   // (512,)
    float* y = (float*)d_out;                 // (8, 512, 4096)

    shift_fused<<<dim3(BATCH * D_MODEL), dim3(NT), 0, stream>>>(u, B, C, D, y);
}

// Round 4
// 120.392 us; speedup vs baseline: 1.3072x; 1.3072x over previous
//
#include <hip/hip_runtime.h>
#include <hip/hip_bf16.h>

// Shift SSM == causal 64-tap FIR per channel + skip (D folded into tap 0).
// R4: MFMA formulation. Per 256 outputs: Y[m][i] = sum_p A[m][p] * T[p][i]
// with A[m][p] = u[base + 16m - 64 + p] (Toeplitz windows from a linear bf16
// LDS row) and T[p][i] = K[64+i-p] (banded 96x16 tap matrix, in registers).
// 3x mfma_f32_16x16x32_bf16 per 16x16 tile. Kernel is then HBM-bound.

#define D_MODEL 512
#define D_STATE 64
#define BATCH   8
#define SEQ_L   4096
#define NT      256

typedef short           s16x8 __attribute__((ext_vector_type(8)));
typedef unsigned short  u16;
typedef u16             u16x4 __attribute__((ext_vector_type(4)));
typedef u16             u16x8 __attribute__((ext_vector_type(8)));
typedef float           f32x4 __attribute__((ext_vector_type(4)));

// XOR swizzle on 16B LDS chunks (applied at write AND read): spreads the
// stride-32B a-frag reads / stride-64B staging writes across bank groups.
__device__ __forceinline__ int SW(int g) { return g ^ ((g >> 3) & 7); }

__device__ __forceinline__ u16 f2bf(float f) {   // RNE float -> bf16 bits
    unsigned v = __builtin_bit_cast(unsigned, f);
    return (u16)((v + 0x7FFFu + ((v >> 16) & 1u)) >> 16);
}

__global__ void __launch_bounds__(NT)
shift_mfma(const float* __restrict__ u, const float* __restrict__ B,
           const float* __restrict__ C, const float* __restrict__ D,
           float* __restrict__ y) {
    const int row = blockIdx.x;              // b*512 + h
    const int h   = row & (D_MODEL - 1);
    const float* __restrict__ urow = u + (size_t)row * SEQ_L;
    float* __restrict__ yrow       = y + (size_t)row * SEQ_L;

    // bf16 row with 64-elem front halo + zero tail; 536 chunks of 8 elems.
    __shared__ u16   ub[536 * 8];
    __shared__ float Bs[64];
    __shared__ float Cs[128];                // zero-padded
    __shared__ float Kf[64];

    const int t = threadIdx.x;

    // ---- stage B, C rows ----
    if (t < 16) {
        ((float4*)Bs)[t] = ((const float4*)(B + h * D_STATE))[t];
    } else if (t < 48) {
        const int j = t - 16;
        ((float4*)Cs)[j] = (j < 16) ? ((const float4*)(C + h * D_STATE))[j]
                                    : make_float4(0.f, 0.f, 0.f, 0.f);
    }

    // ---- stage u row -> bf16 LDS (coalesced float4, swizzled b64 writes) ----
    #pragma unroll
    for (int j = 0; j < 4; ++j) {
        const float4 v = *(const float4*)(urow + 4 * t + 1024 * j);
        u16x4 pk = { f2bf(v.x), f2bf(v.y), f2bf(v.z), f2bf(v.w) };
        const int byte = 128 + 8 * t + 2048 * j;        // halo offset 128 B
        const int sb   = (SW(byte >> 4) << 4) | (byte & 8);
        *(u16x4*)((char*)ub + sb) = pk;
    }
    // halo zeros: front chunks 0..7 (elems L<64), tail chunks 520..531
    if (t < 8) {
        u16x8 z = {0,0,0,0,0,0,0,0};
        *(u16x8*)((char*)ub + (SW(t) << 4)) = z;
    } else if (t < 20) {
        u16x8 z = {0,0,0,0,0,0,0,0};
        const int g = 520 + (t - 8);
        *(u16x8*)((char*)ub + (SW(g) << 4)) = z;
    }
    __syncthreads();

    // ---- taps: K[k] = sum_j B[j] C[k+j]  (+D at k=0) ----
    if (t < D_STATE) {
        float s = 0.f;
        #pragma unroll
        for (int j = 0; j < D_STATE; ++j) s = fmaf(Bs[j], Cs[t + j], s);
        if (t == 0) s += D[h];
        Kf[t] = s;
    }
    __syncthreads();

    // ---- b-frags: T[p][i] = K[64+i-p], p = 32c + 8q + j, i = lane&15 ----
    const int l = t & 63;
    const int n = l & 15;                    // output position within tile
    const int q = l >> 4;                    // k-quad
    s16x8 bfr[3];
    #pragma unroll
    for (int c = 0; c < 3; ++c) {
        #pragma unroll
        for (int j = 0; j < 8; ++j) {
            const int p = 32 * c + 8 * q + j;
            const int k = 64 + n - p;
            const float v = (k >= 0 && k < D_STATE) ? Kf[k] : 0.f;
            bfr[c][j] = (short)f2bf(v);
        }
    }

    // ---- 4 tiles (of 256 outputs) per wave ----
    const int wbase = 1024 * (t >> 6);
    #pragma unroll
    for (int tt = 0; tt < 4; ++tt) {
        const int base = wbase + 256 * tt;
        f32x4 acc = {0.f, 0.f, 0.f, 0.f};
        #pragma unroll
        for (int c = 0; c < 3; ++c) {
            // A[m][p]: lane m = l&15 reads 8 consecutive bf16 at
            // L = base + 16m + 32c + 8q  (window start -64 cancels halo +64)
            const int L  = base + 16 * n + 32 * c + 8 * q;
            const int sb = SW(L >> 3) << 4;
            const s16x8 a = *(const s16x8*)((const char*)ub + sb);
            acc = __builtin_amdgcn_mfma_f32_16x16x32_bf16(a, bfr[c], acc, 0, 0, 0);
        }
        // D[m][i]: m = 4q + r (row), i = n (col); out = base + 16m + i
        #pragma unroll
        for (int r = 0; r < 4; ++r)
            yrow[base + 16 * (4 * q + r) + n] = acc[r];
    }
}

extern "C" void kernel_launch(void* const* d_in, const int* in_sizes, int n_in,
                              void* d_out, int out_size, void* d_ws, size_t ws_size,
                              hipStream_t stream) {
    const float* u = (const float*)d_in[0];   // (8, 512, 4096)
    const float* B = (const float*)d_in[1];   // (512, 64)
    const float* C = (const float*)d_in[2];   // (1, 512, 64)
    const float* D = (const float*)d_in[3];   // (512,)
    float* y = (float*)d_out;                 // (8, 512, 4096)

    shift_mfma<<<dim3(BATCH * D_MODEL), dim3(NT), 0, stream>>>(u, B, C, D, y);
}